// Round 1
// baseline (13701.610 us; speedup 1.0000x reference)
//
#include <hip/hip_runtime.h>

// GraphSAGE: x(524288,256) -> FC relu -> 3x sage_conv layers -> out(8192,64)
constexpr int N0c = 524288, N1c = 262144, N2c = 65536, N3c = 8192;

// C[M x N] = act( A1[M x 256] @ W1[256 x N] (+ A2 @ W2) + b[N] )
// tile 64x64, BK=32, 256 threads, 4x4 micro-tile per thread
template<bool RELU, bool DUAL>
__global__ __launch_bounds__(256)
void gemm_k(const float* __restrict__ A1, const float* __restrict__ A2,
            const float* __restrict__ W1, const float* __restrict__ W2,
            const float* __restrict__ bias, float* __restrict__ C,
            int M, int N)
{
    __shared__ float As1[64][36];              // pad 32->36: 16B-aligned rows, no read conflicts
    __shared__ float Bs1[32][64];
    __shared__ float As2[DUAL ? 64 : 1][36];
    __shared__ float Bs2[DUAL ? 32 : 1][64];

    const int t  = threadIdx.x;
    const int tx = t & 15, ty = t >> 4;
    const long row0 = (long)blockIdx.x * 64;
    const int  col0 = blockIdx.y * 64;

    // global->LDS load mapping (contiguous float4 per lane)
    const int a_r = t >> 3;            // 0..31 (+32 for second half)
    const int a_c = (t << 2) & 31;
    const int b_r = t >> 4;            // 0..15 (+16 for second half)
    const int b_c = (t << 2) & 63;

    float acc[4][4] = {};

    for (int k0 = 0; k0 < 256; k0 += 32) {
        // issue global loads before the barrier (overlap with prev compute)
        const float4 a0 = *(const float4*)&A1[(row0 + a_r)      * 256 + k0 + a_c];
        const float4 a1 = *(const float4*)&A1[(row0 + 32 + a_r) * 256 + k0 + a_c];
        const float4 w0 = *(const float4*)&W1[(long)(k0 + b_r)      * N + col0 + b_c];
        const float4 w1 = *(const float4*)&W1[(long)(k0 + 16 + b_r) * N + col0 + b_c];
        float4 c0, c1, v0, v1;
        if constexpr (DUAL) {
            c0 = *(const float4*)&A2[(row0 + a_r)      * 256 + k0 + a_c];
            c1 = *(const float4*)&A2[(row0 + 32 + a_r) * 256 + k0 + a_c];
            v0 = *(const float4*)&W2[(long)(k0 + b_r)      * N + col0 + b_c];
            v1 = *(const float4*)&W2[(long)(k0 + 16 + b_r) * N + col0 + b_c];
        }
        __syncthreads();   // previous iteration's LDS reads done
        *(float4*)&As1[a_r][a_c]      = a0;
        *(float4*)&As1[a_r + 32][a_c] = a1;
        *(float4*)&Bs1[b_r][b_c]      = w0;
        *(float4*)&Bs1[b_r + 16][b_c] = w1;
        if constexpr (DUAL) {
            *(float4*)&As2[a_r][a_c]      = c0;
            *(float4*)&As2[a_r + 32][a_c] = c1;
            *(float4*)&Bs2[b_r][b_c]      = v0;
            *(float4*)&Bs2[b_r + 16][b_c] = v1;
        }
        __syncthreads();

        #pragma unroll
        for (int kk = 0; kk < 32; ++kk) {
            const float4 bv = *(const float4*)&Bs1[kk][tx << 2];
            float av[4];
            #pragma unroll
            for (int i = 0; i < 4; ++i) av[i] = As1[(ty << 2) + i][kk];
            #pragma unroll
            for (int i = 0; i < 4; ++i) {
                acc[i][0] += av[i] * bv.x;
                acc[i][1] += av[i] * bv.y;
                acc[i][2] += av[i] * bv.z;
                acc[i][3] += av[i] * bv.w;
            }
            if constexpr (DUAL) {
                const float4 bw = *(const float4*)&Bs2[kk][tx << 2];
                float aw[4];
                #pragma unroll
                for (int i = 0; i < 4; ++i) aw[i] = As2[(ty << 2) + i][kk];
                #pragma unroll
                for (int i = 0; i < 4; ++i) {
                    acc[i][0] += aw[i] * bw.x;
                    acc[i][1] += aw[i] * bw.y;
                    acc[i][2] += aw[i] * bw.z;
                    acc[i][3] += aw[i] * bw.w;
                }
            }
        }
    }

    const int cc = col0 + (tx << 2);
    const float4 bv = *(const float4*)&bias[cc];
    #pragma unroll
    for (int i = 0; i < 4; ++i) {
        const long r = row0 + (ty << 2) + i;
        float4 o;
        o.x = acc[i][0] + bv.x;
        o.y = acc[i][1] + bv.y;
        o.z = acc[i][2] + bv.z;
        o.w = acc[i][3] + bv.w;
        if constexpr (RELU) {
            o.x = fmaxf(o.x, 0.f); o.y = fmaxf(o.y, 0.f);
            o.z = fmaxf(o.z, 0.f); o.w = fmaxf(o.w, 0.f);
        }
        *(float4*)&C[r * N + cc] = o;
    }
}

// one wave per edge: gather h[src] row (256 f32), atomic-add into agg[dst]
__global__ __launch_bounds__(256)
void scatter_k(const float* __restrict__ h, const int* __restrict__ src,
               const int* __restrict__ dst, float* __restrict__ agg, int E)
{
    const int gw   = (blockIdx.x << 2) | (threadIdx.x >> 6);
    const int lane = threadIdx.x & 63;
    if (gw >= E) return;
    const int s = src[gw], d = dst[gw];
    const float4 v = *(const float4*)&h[(size_t)s * 256 + (lane << 2)];
    float* o = &agg[(size_t)d * 256 + (lane << 2)];
    unsafeAtomicAdd(o + 0, v.x);
    unsafeAtomicAdd(o + 1, v.y);
    unsafeAtomicAdd(o + 2, v.z);
    unsafeAtomicAdd(o + 3, v.w);
}

__global__ __launch_bounds__(256)
void count_k(const int* __restrict__ dst, float* __restrict__ cnt, int E)
{
    const int i = blockIdx.x * 256 + threadIdx.x;
    if (i < E) unsafeAtomicAdd(&cnt[dst[i]], 1.0f);
}

// agg[i] /= max(cnt[row],1);  total = n_rows*256, grid = n_rows
__global__ __launch_bounds__(256)
void mean_k(float* __restrict__ agg, const float* __restrict__ cnt)
{
    const int i = blockIdx.x * 256 + threadIdx.x;
    const float c = cnt[i >> 8];
    agg[i] = agg[i] / fmaxf(c, 1.0f);
}

extern "C" void kernel_launch(void* const* d_in, const int* in_sizes, int n_in,
                              void* d_out, int out_size, void* d_ws, size_t ws_size,
                              hipStream_t stream)
{
    const float* x    = (const float*)d_in[0];
    const int*   src0 = (const int*)d_in[1];
    const int*   dst0 = (const int*)d_in[2];
    const int*   src1 = (const int*)d_in[3];
    const int*   dst1 = (const int*)d_in[4];
    const int*   src2 = (const int*)d_in[5];
    const int*   dst2 = (const int*)d_in[6];
    const float* Wfc  = (const float*)d_in[10];
    const float* bfc  = (const float*)d_in[11];
    const float* Ws0  = (const float*)d_in[12];
    const float* Wn0  = (const float*)d_in[13];
    const float* b0   = (const float*)d_in[14];
    const float* Ws1  = (const float*)d_in[15];
    const float* Wn1  = (const float*)d_in[16];
    const float* b1   = (const float*)d_in[17];
    const float* Ws2  = (const float*)d_in[18];
    const float* Wn2  = (const float*)d_in[19];
    const float* b2   = (const float*)d_in[20];
    const int E0 = in_sizes[1], E1 = in_sizes[3], E2 = in_sizes[5];

    char* ws = (char*)d_ws;
    float* h0  = (float*)ws;                        // 512 MiB  (N0*256 f32)
    float* h1  = (float*)(ws + 536870912ULL);       // 256 MiB  (N1*256 f32)
    float* agg = (float*)(ws + 805306368ULL);       // 256 MiB  (max N1*256 f32, reused)
    float* cnt = (float*)(ws + 1073741824ULL);      // 1 MiB    (max N1 f32, reused)
    float* h2  = h0;                                // reuse h0 region after layer 1

    const dim3 blk(256);

    // h0 = relu(x @ Wfc + bfc)
    gemm_k<true, false><<<dim3(N0c / 64, 4), blk, 0, stream>>>(
        x, nullptr, Wfc, nullptr, bfc, h0, N0c, 256);

    // ---- layer 0: N0 -> N1 ----
    hipMemsetAsync(agg, 0, (size_t)N1c * 256 * 4, stream);
    hipMemsetAsync(cnt, 0, (size_t)N1c * 4, stream);
    scatter_k<<<dim3((E0 + 3) / 4), blk, 0, stream>>>(h0, src0, dst0, agg, E0);
    count_k<<<dim3((E0 + 255) / 256), blk, 0, stream>>>(dst0, cnt, E0);
    mean_k<<<dim3(N1c), blk, 0, stream>>>(agg, cnt);
    gemm_k<true, true><<<dim3(N1c / 64, 4), blk, 0, stream>>>(
        h0, agg, Ws0, Wn0, b0, h1, N1c, 256);

    // ---- layer 1: N1 -> N2 ----
    hipMemsetAsync(agg, 0, (size_t)N2c * 256 * 4, stream);
    hipMemsetAsync(cnt, 0, (size_t)N2c * 4, stream);
    scatter_k<<<dim3((E1 + 3) / 4), blk, 0, stream>>>(h1, src1, dst1, agg, E1);
    count_k<<<dim3((E1 + 255) / 256), blk, 0, stream>>>(dst1, cnt, E1);
    mean_k<<<dim3(N2c), blk, 0, stream>>>(agg, cnt);
    gemm_k<true, true><<<dim3(N2c / 64, 4), blk, 0, stream>>>(
        h1, agg, Ws1, Wn1, b1, h2, N2c, 256);

    // ---- layer 2: N2 -> N3, out width 64, no relu ----
    hipMemsetAsync(agg, 0, (size_t)N3c * 256 * 4, stream);
    hipMemsetAsync(cnt, 0, (size_t)N3c * 4, stream);
    scatter_k<<<dim3((E2 + 3) / 4), blk, 0, stream>>>(h2, src2, dst2, agg, E2);
    count_k<<<dim3((E2 + 255) / 256), blk, 0, stream>>>(dst2, cnt, E2);
    mean_k<<<dim3(N3c), blk, 0, stream>>>(agg, cnt);
    gemm_k<false, true><<<dim3(N3c / 64, 1), blk, 0, stream>>>(
        h2, agg, Ws2, Wn2, b2, (float*)d_out, N3c, 64);
}

// Round 2
// 2998.888 us; speedup vs baseline: 4.5689x; 4.5689x over previous
//
#include <hip/hip_runtime.h>

// GraphSAGE: x(524288,256) -> FC relu -> 3x sage_conv layers -> out(8192,64)
constexpr int N0c = 524288, N1c = 262144, N2c = 65536, N3c = 8192;

// C[M x N] = act( A1[M x 256] @ W1[256 x N] (+ A2 @ W2) + b[N] )
// tile 64x64, BK=32, 256 threads, 4x4 micro-tile per thread
template<bool RELU, bool DUAL>
__global__ __launch_bounds__(256)
void gemm_k(const float* __restrict__ A1, const float* __restrict__ A2,
            const float* __restrict__ W1, const float* __restrict__ W2,
            const float* __restrict__ bias, float* __restrict__ C,
            int M, int N)
{
    __shared__ float As1[64][36];
    __shared__ float Bs1[32][64];
    __shared__ float As2[DUAL ? 64 : 1][36];
    __shared__ float Bs2[DUAL ? 32 : 1][64];

    const int t  = threadIdx.x;
    const int tx = t & 15, ty = t >> 4;
    const long row0 = (long)blockIdx.x * 64;
    const int  col0 = blockIdx.y * 64;

    const int a_r = t >> 3;
    const int a_c = (t << 2) & 31;
    const int b_r = t >> 4;
    const int b_c = (t << 2) & 63;

    float acc[4][4] = {};

    for (int k0 = 0; k0 < 256; k0 += 32) {
        const float4 a0 = *(const float4*)&A1[(row0 + a_r)      * 256 + k0 + a_c];
        const float4 a1 = *(const float4*)&A1[(row0 + 32 + a_r) * 256 + k0 + a_c];
        const float4 w0 = *(const float4*)&W1[(long)(k0 + b_r)      * N + col0 + b_c];
        const float4 w1 = *(const float4*)&W1[(long)(k0 + 16 + b_r) * N + col0 + b_c];
        float4 c0, c1, v0, v1;
        if constexpr (DUAL) {
            c0 = *(const float4*)&A2[(row0 + a_r)      * 256 + k0 + a_c];
            c1 = *(const float4*)&A2[(row0 + 32 + a_r) * 256 + k0 + a_c];
            v0 = *(const float4*)&W2[(long)(k0 + b_r)      * N + col0 + b_c];
            v1 = *(const float4*)&W2[(long)(k0 + 16 + b_r) * N + col0 + b_c];
        }
        __syncthreads();
        *(float4*)&As1[a_r][a_c]      = a0;
        *(float4*)&As1[a_r + 32][a_c] = a1;
        *(float4*)&Bs1[b_r][b_c]      = w0;
        *(float4*)&Bs1[b_r + 16][b_c] = w1;
        if constexpr (DUAL) {
            *(float4*)&As2[a_r][a_c]      = c0;
            *(float4*)&As2[a_r + 32][a_c] = c1;
            *(float4*)&Bs2[b_r][b_c]      = v0;
            *(float4*)&Bs2[b_r + 16][b_c] = v1;
        }
        __syncthreads();

        #pragma unroll
        for (int kk = 0; kk < 32; ++kk) {
            const float4 bv = *(const float4*)&Bs1[kk][tx << 2];
            float av[4];
            #pragma unroll
            for (int i = 0; i < 4; ++i) av[i] = As1[(ty << 2) + i][kk];
            #pragma unroll
            for (int i = 0; i < 4; ++i) {
                acc[i][0] += av[i] * bv.x;
                acc[i][1] += av[i] * bv.y;
                acc[i][2] += av[i] * bv.z;
                acc[i][3] += av[i] * bv.w;
            }
            if constexpr (DUAL) {
                const float4 bw = *(const float4*)&Bs2[kk][tx << 2];
                float aw[4];
                #pragma unroll
                for (int i = 0; i < 4; ++i) aw[i] = As2[(ty << 2) + i][kk];
                #pragma unroll
                for (int i = 0; i < 4; ++i) {
                    acc[i][0] += aw[i] * bw.x;
                    acc[i][1] += aw[i] * bw.y;
                    acc[i][2] += aw[i] * bw.z;
                    acc[i][3] += aw[i] * bw.w;
                }
            }
        }
    }

    const int cc = col0 + (tx << 2);
    const float4 bv = *(const float4*)&bias[cc];
    #pragma unroll
    for (int i = 0; i < 4; ++i) {
        const long r = row0 + (ty << 2) + i;
        float4 o;
        o.x = acc[i][0] + bv.x;
        o.y = acc[i][1] + bv.y;
        o.z = acc[i][2] + bv.z;
        o.w = acc[i][3] + bv.w;
        if constexpr (RELU) {
            o.x = fmaxf(o.x, 0.f); o.y = fmaxf(o.y, 0.f);
            o.z = fmaxf(o.z, 0.f); o.w = fmaxf(o.w, 0.f);
        }
        *(float4*)&C[r * N + cc] = o;
    }
}

// ---- CSR build: counting sort of edges by dst ----

__global__ __launch_bounds__(256)
void hist_k(const int* __restrict__ dst, int* __restrict__ hist, int E)
{
    const int i = blockIdx.x * 256 + threadIdx.x;
    if (i < E) atomicAdd(&hist[dst[i]], 1);
}

// block scans 1024 elements (4/thread); writes per-element exclusive prefix + block total
__global__ __launch_bounds__(256)
void scan1_k(const int* __restrict__ hist, int* __restrict__ offs,
             int* __restrict__ bsum, int n)
{
    __shared__ int sm[256];
    const int t = threadIdx.x;
    const int base = blockIdx.x * 1024 + t * 4;
    int4 v = make_int4(0, 0, 0, 0);
    if (base < n) v = *(const int4*)&hist[base];
    const int s = v.x + v.y + v.z + v.w;
    int val = s;
    sm[t] = val; __syncthreads();
    #pragma unroll
    for (int off = 1; off < 256; off <<= 1) {
        const int add = (t >= off) ? sm[t - off] : 0;
        __syncthreads();
        val += add;
        sm[t] = val;
        __syncthreads();
    }
    const int excl = val - s;
    if (base < n) {
        offs[base]     = excl;
        offs[base + 1] = excl + v.x;
        offs[base + 2] = excl + v.x + v.y;
        offs[base + 3] = excl + v.x + v.y + v.z;
    }
    if (t == 255) bsum[blockIdx.x] = val;
}

// single block: exclusive scan of block totals (nb <= 256)
__global__ __launch_bounds__(256)
void scan2_k(int* __restrict__ bsum, int nb)
{
    __shared__ int sm[256];
    const int t = threadIdx.x;
    const int s = (t < nb) ? bsum[t] : 0;
    int val = s;
    sm[t] = val; __syncthreads();
    #pragma unroll
    for (int off = 1; off < 256; off <<= 1) {
        const int add = (t >= off) ? sm[t - off] : 0;
        __syncthreads();
        val += add;
        sm[t] = val;
        __syncthreads();
    }
    if (t < nb) bsum[t] = val - s;
}

__global__ __launch_bounds__(256)
void scan3_k(int* __restrict__ offs, const int* __restrict__ bsum)
{
    const int i = blockIdx.x * 256 + threadIdx.x;
    offs[i] += bsum[i >> 10];
}

// place src indices into dst-sorted order; consumes hist (decrements to 0)
__global__ __launch_bounds__(256)
void fill_k(const int* __restrict__ src, const int* __restrict__ dst,
            const int* __restrict__ offs, int* __restrict__ hist,
            int* __restrict__ ssrc, int E)
{
    const int i = blockIdx.x * 256 + threadIdx.x;
    if (i < E) {
        const int d = dst[i];
        const int p = atomicAdd(&hist[d], -1) - 1;   // position within segment
        ssrc[offs[d] + p] = src[i];
    }
}

// one wave per dst row: gather+sum h[src] rows, divide by deg, store (no atomics)
__global__ __launch_bounds__(256)
void agg_k(const float* __restrict__ h, const int* __restrict__ ssrc,
           const int* __restrict__ offs, float* __restrict__ agg, int n, int E)
{
    const int w    = blockIdx.x * 4 + (threadIdx.x >> 6);
    const int lane = threadIdx.x & 63;
    if (w >= n) return;
    const int beg = offs[w];
    const int end = (w == n - 1) ? E : offs[w + 1];
    float4 acc = make_float4(0.f, 0.f, 0.f, 0.f);
    int j = beg;
    for (; j + 1 < end; j += 2) {          // 2 independent loads in flight
        const int s0 = ssrc[j], s1 = ssrc[j + 1];
        const float4 v0 = *(const float4*)&h[(size_t)s0 * 256 + (lane << 2)];
        const float4 v1 = *(const float4*)&h[(size_t)s1 * 256 + (lane << 2)];
        acc.x += v0.x + v1.x; acc.y += v0.y + v1.y;
        acc.z += v0.z + v1.z; acc.w += v0.w + v1.w;
    }
    if (j < end) {
        const int s0 = ssrc[j];
        const float4 v0 = *(const float4*)&h[(size_t)s0 * 256 + (lane << 2)];
        acc.x += v0.x; acc.y += v0.y; acc.z += v0.z; acc.w += v0.w;
    }
    const float inv = 1.0f / fmaxf((float)(end - beg), 1.0f);
    acc.x *= inv; acc.y *= inv; acc.z *= inv; acc.w *= inv;
    *(float4*)&agg[(size_t)w * 256 + (lane << 2)] = acc;
}

static void build_and_aggregate(const float* h, const int* src, const int* dst,
                                int n, int E, int* hist, int* offs, int* bsum,
                                int* ssrc, float* agg, hipStream_t stream)
{
    const dim3 blk(256);
    hipMemsetAsync(hist, 0, (size_t)n * 4, stream);
    hist_k<<<dim3((E + 255) / 256), blk, 0, stream>>>(dst, hist, E);
    scan1_k<<<dim3(n / 1024), blk, 0, stream>>>(hist, offs, bsum, n);
    scan2_k<<<dim3(1), blk, 0, stream>>>(bsum, n / 1024);
    scan3_k<<<dim3(n / 256), blk, 0, stream>>>(offs, bsum);
    fill_k<<<dim3((E + 255) / 256), blk, 0, stream>>>(src, dst, offs, hist, ssrc, E);
    agg_k<<<dim3(n / 4), blk, 0, stream>>>(h, ssrc, offs, agg, n, E);
}

extern "C" void kernel_launch(void* const* d_in, const int* in_sizes, int n_in,
                              void* d_out, int out_size, void* d_ws, size_t ws_size,
                              hipStream_t stream)
{
    const float* x    = (const float*)d_in[0];
    const int*   src0 = (const int*)d_in[1];
    const int*   dst0 = (const int*)d_in[2];
    const int*   src1 = (const int*)d_in[3];
    const int*   dst1 = (const int*)d_in[4];
    const int*   src2 = (const int*)d_in[5];
    const int*   dst2 = (const int*)d_in[6];
    const float* Wfc  = (const float*)d_in[10];
    const float* bfc  = (const float*)d_in[11];
    const float* Ws0  = (const float*)d_in[12];
    const float* Wn0  = (const float*)d_in[13];
    const float* b0   = (const float*)d_in[14];
    const float* Ws1  = (const float*)d_in[15];
    const float* Wn1  = (const float*)d_in[16];
    const float* b1   = (const float*)d_in[17];
    const float* Ws2  = (const float*)d_in[18];
    const float* Wn2  = (const float*)d_in[19];
    const float* b2   = (const float*)d_in[20];
    const int E0 = in_sizes[1], E1 = in_sizes[3], E2 = in_sizes[5];

    char* ws = (char*)d_ws;
    float* h0   = (float*)ws;                          // 512 MiB
    float* h1   = (float*)(ws + (512ULL << 20));       // 256 MiB
    float* agg  = (float*)(ws + (768ULL << 20));       // 256 MiB (reused per layer)
    int*   hist = (int*)  (ws + (1024ULL << 20));      // 1 MiB
    int*   offs = (int*)  (ws + (1025ULL << 20));      // 1 MiB
    int*   bsum = (int*)  (ws + (1026ULL << 20));      // 1 KiB
    int*   ssrc = (int*)  (ws + (1027ULL << 20));      // <= 10.5 MiB
    float* h2   = h0;                                  // reuse h0 after layer 1

    const dim3 blk(256);

    // h0 = relu(x @ Wfc + bfc)
    gemm_k<true, false><<<dim3(N0c / 64, 4), blk, 0, stream>>>(
        x, nullptr, Wfc, nullptr, bfc, h0, N0c, 256);

    // ---- layer 0: N0 -> N1 ----
    build_and_aggregate(h0, src0, dst0, N1c, E0, hist, offs, bsum, ssrc, agg, stream);
    gemm_k<true, true><<<dim3(N1c / 64, 4), blk, 0, stream>>>(
        h0, agg, Ws0, Wn0, b0, h1, N1c, 256);

    // ---- layer 1: N1 -> N2 ----
    build_and_aggregate(h1, src1, dst1, N2c, E1, hist, offs, bsum, ssrc, agg, stream);
    gemm_k<true, true><<<dim3(N2c / 64, 4), blk, 0, stream>>>(
        h1, agg, Ws1, Wn1, b1, h2, N2c, 256);

    // ---- layer 2: N2 -> N3, out width 64, no relu ----
    build_and_aggregate(h2, src2, dst2, N3c, E2, hist, offs, bsum, ssrc, agg, stream);
    gemm_k<false, true><<<dim3(N3c / 64, 1), blk, 0, stream>>>(
        h2, agg, Ws2, Wn2, b2, (float*)d_out, N3c, 64);
}

// Round 4
// 1512.604 us; speedup vs baseline: 9.0583x; 1.9826x over previous
//
#include <hip/hip_runtime.h>

// GraphSAGE: x(524288,256) -> FC relu -> 3x sage_conv -> out(8192,64)
// bf16 activations + register-resident MFMA GEMMs (no LDS), CSR pull-aggregation.
constexpr int N0c = 524288, N1c = 262144, N2c = 65536, N3c = 8192;

typedef __attribute__((ext_vector_type(8))) short   bf16x8;
typedef __attribute__((ext_vector_type(4))) float   f32x4;
typedef __attribute__((ext_vector_type(4))) unsigned short u16x4;

__device__ inline unsigned short f2bf(float f) {
    union { float f; unsigned u; } v; v.f = f;
    unsigned r = v.u + 0x7FFF + ((v.u >> 16) & 1);   // RNE
    return (unsigned short)(r >> 16);
}
__device__ inline float bf2f(unsigned short u) {
    union { unsigned u; float f; } v; v.u = ((unsigned)u) << 16;
    return v.f;
}

// transpose + cast one weight: Wt[n][k] = bf16(W[k][n]); K is always 256 here
__global__ __launch_bounds__(256)
void wconv_k(const float* __restrict__ W, unsigned short* __restrict__ Wt, int K, int N)
{
    const int i = blockIdx.x * 256 + threadIdx.x;   // over K*N
    if (i >= K * N) return;
    const int k = i / N, n = i % N;
    Wt[n * K + k] = f2bf(W[i]);
}

__device__ inline bf16x8 pack_bf8(const float* p) {
    const f32x4 u = *(const f32x4*)p;
    const f32x4 v = *(const f32x4*)(p + 4);
    bf16x8 t;
    #pragma unroll
    for (int j = 0; j < 4; ++j) {
        t[j]     = (short)f2bf(u[j]);
        t[j + 4] = (short)f2bf(v[j]);
    }
    return t;
}

// C[M x NT*16] = act( A1 @ Wt1^T (+ A2 @ Wt2^T) + b ), K=256 fixed.
// Wt is [N][K] bf16 (pre-transposed) -> contiguous 16B B-fragments from L2.
// block = 256 thr = 4 waves; wave owns 32 rows (2 x 16-row MFMA strips).
template<int NT, bool RELU, bool DUAL, bool A_F32, bool OUT_BF16>
__global__ __launch_bounds__(256, 2)
void gemm_mfma(const void* __restrict__ A1v, const void* __restrict__ A2v,
               const unsigned short* __restrict__ Wt1,
               const unsigned short* __restrict__ Wt2,
               const float* __restrict__ bias, void* __restrict__ Cv, long M)
{
    constexpr int N = NT * 16;
    const int lane = threadIdx.x & 63;
    const int wv   = threadIdx.x >> 6;
    const long row0 = (long)blockIdx.x * 128 + wv * 32;
    const int col = lane & 15;     // n-in-tile (B/C) == m-in-strip (A)
    const int kg  = lane >> 4;     // k-group: k = kg*8 + j

    const unsigned short* A1h = (const unsigned short*)A1v;
    const float*          A1f = (const float*)A1v;
    const unsigned short* A2h = (const unsigned short*)A2v;

    f32x4 acc[NT][2];
    #pragma unroll
    for (int nt = 0; nt < NT; ++nt)
        #pragma unroll
        for (int mi = 0; mi < 2; ++mi)
            acc[nt][mi] = (f32x4){0.f, 0.f, 0.f, 0.f};

    #pragma unroll
    for (int k0 = 0; k0 < 256; k0 += 32) {
        bf16x8 a1[2], a2[2];
        #pragma unroll
        for (int mi = 0; mi < 2; ++mi) {
            const long r = row0 + mi * 16 + col;
            if constexpr (A_F32)
                a1[mi] = pack_bf8(&A1f[r * 256 + k0 + kg * 8]);
            else
                a1[mi] = *(const bf16x8*)&A1h[r * 256 + k0 + kg * 8];
            if constexpr (DUAL)
                a2[mi] = *(const bf16x8*)&A2h[r * 256 + k0 + kg * 8];
        }
        #pragma unroll
        for (int nt = 0; nt < NT; ++nt) {
            const bf16x8 b1 = *(const bf16x8*)&Wt1[(nt * 16 + col) * 256 + k0 + kg * 8];
            #pragma unroll
            for (int mi = 0; mi < 2; ++mi)
                acc[nt][mi] = __builtin_amdgcn_mfma_f32_16x16x32_bf16(a1[mi], b1, acc[nt][mi], 0, 0, 0);
            if constexpr (DUAL) {
                const bf16x8 b2 = *(const bf16x8*)&Wt2[(nt * 16 + col) * 256 + k0 + kg * 8];
                #pragma unroll
                for (int mi = 0; mi < 2; ++mi)
                    acc[nt][mi] = __builtin_amdgcn_mfma_f32_16x16x32_bf16(a2[mi], b2, acc[nt][mi], 0, 0, 0);
            }
        }
    }

    #pragma unroll
    for (int nt = 0; nt < NT; ++nt) {
        const int c = nt * 16 + col;
        const float bb = bias[c];
        #pragma unroll
        for (int mi = 0; mi < 2; ++mi) {
            #pragma unroll
            for (int r = 0; r < 4; ++r) {
                const long row = row0 + mi * 16 + kg * 4 + r;
                float o = acc[nt][mi][r] + bb;
                if constexpr (RELU) o = fmaxf(o, 0.f);
                if constexpr (OUT_BF16)
                    ((unsigned short*)Cv)[row * N + c] = f2bf(o);
                else
                    ((float*)Cv)[row * N + c] = o;
            }
        }
    }
}

// ---- CSR build: counting sort of edges by dst ----

__global__ __launch_bounds__(256)
void hist_k(const int* __restrict__ dst, int* __restrict__ hist, int E)
{
    const int i = blockIdx.x * 256 + threadIdx.x;
    if (i < E) atomicAdd(&hist[dst[i]], 1);
}

__global__ __launch_bounds__(256)
void scan1_k(const int* __restrict__ hist, int* __restrict__ offs,
             int* __restrict__ bsum, int n)
{
    __shared__ int sm[256];
    const int t = threadIdx.x;
    const int base = blockIdx.x * 1024 + t * 4;
    int4 v = make_int4(0, 0, 0, 0);
    if (base < n) v = *(const int4*)&hist[base];
    const int s = v.x + v.y + v.z + v.w;
    int val = s;
    sm[t] = val; __syncthreads();
    #pragma unroll
    for (int off = 1; off < 256; off <<= 1) {
        const int add = (t >= off) ? sm[t - off] : 0;
        __syncthreads();
        val += add;
        sm[t] = val;
        __syncthreads();
    }
    const int excl = val - s;
    if (base < n) {
        offs[base]     = excl;
        offs[base + 1] = excl + v.x;
        offs[base + 2] = excl + v.x + v.y;
        offs[base + 3] = excl + v.x + v.y + v.z;
    }
    if (t == 255) bsum[blockIdx.x] = val;
}

__global__ __launch_bounds__(256)
void scan2_k(int* __restrict__ bsum, int nb)
{
    __shared__ int sm[256];
    const int t = threadIdx.x;
    const int s = (t < nb) ? bsum[t] : 0;
    int val = s;
    sm[t] = val; __syncthreads();
    #pragma unroll
    for (int off = 1; off < 256; off <<= 1) {
        const int add = (t >= off) ? sm[t - off] : 0;
        __syncthreads();
        val += add;
        sm[t] = val;
        __syncthreads();
    }
    if (t < nb) bsum[t] = val - s;
}

__global__ __launch_bounds__(256)
void scan3_k(int* __restrict__ offs, const int* __restrict__ bsum)
{
    const int i = blockIdx.x * 256 + threadIdx.x;
    offs[i] += bsum[i >> 10];
}

__global__ __launch_bounds__(256)
void fill_k(const int* __restrict__ src, const int* __restrict__ dst,
            const int* __restrict__ offs, int* __restrict__ hist,
            int* __restrict__ ssrc, int E)
{
    const int i = blockIdx.x * 256 + threadIdx.x;
    if (i < E) {
        const int d = dst[i];
        const int p = atomicAdd(&hist[d], -1) - 1;
        ssrc[offs[d] + p] = src[i];
    }
}

// one wave per dst row: gather+mean bf16 h[src] rows (512 B each), no atomics
__global__ __launch_bounds__(256)
void agg_k(const unsigned short* __restrict__ h, const int* __restrict__ ssrc,
           const int* __restrict__ offs, unsigned short* __restrict__ agg,
           int n, int E)
{
    const int w    = blockIdx.x * 4 + (threadIdx.x >> 6);
    const int lane = threadIdx.x & 63;
    if (w >= n) return;
    const int beg = offs[w];
    const int end = (w == n - 1) ? E : offs[w + 1];
    float acc[4] = {0.f, 0.f, 0.f, 0.f};
    int j = beg;
    for (; j + 3 < end; j += 4) {                  // 4 loads in flight
        const int s0 = ssrc[j], s1 = ssrc[j+1], s2 = ssrc[j+2], s3 = ssrc[j+3];
        const u16x4 v0 = *(const u16x4*)&h[(size_t)s0 * 256 + lane * 4];
        const u16x4 v1 = *(const u16x4*)&h[(size_t)s1 * 256 + lane * 4];
        const u16x4 v2 = *(const u16x4*)&h[(size_t)s2 * 256 + lane * 4];
        const u16x4 v3 = *(const u16x4*)&h[(size_t)s3 * 256 + lane * 4];
        #pragma unroll
        for (int c = 0; c < 4; ++c)
            acc[c] += bf2f(v0[c]) + bf2f(v1[c]) + bf2f(v2[c]) + bf2f(v3[c]);
    }
    for (; j < end; ++j) {
        const u16x4 v0 = *(const u16x4*)&h[(size_t)ssrc[j] * 256 + lane * 4];
        #pragma unroll
        for (int c = 0; c < 4; ++c) acc[c] += bf2f(v0[c]);
    }
    const float inv = 1.0f / fmaxf((float)(end - beg), 1.0f);
    u16x4 o;
    #pragma unroll
    for (int c = 0; c < 4; ++c) o[c] = f2bf(acc[c] * inv);
    *(u16x4*)&agg[(size_t)w * 256 + lane * 4] = o;
}

static void build_and_aggregate(const unsigned short* h, const int* src, const int* dst,
                                int n, int E, int* hist, int* offs, int* bsum,
                                int* ssrc, unsigned short* agg, hipStream_t stream)
{
    const dim3 blk(256);
    hipMemsetAsync(hist, 0, (size_t)n * 4, stream);
    hist_k<<<dim3((E + 255) / 256), blk, 0, stream>>>(dst, hist, E);
    scan1_k<<<dim3(n / 1024), blk, 0, stream>>>(hist, offs, bsum, n);
    scan2_k<<<dim3(1), blk, 0, stream>>>(bsum, n / 1024);
    scan3_k<<<dim3(n / 256), blk, 0, stream>>>(offs, bsum);
    fill_k<<<dim3((E + 255) / 256), blk, 0, stream>>>(src, dst, offs, hist, ssrc, E);
    agg_k<<<dim3(n / 4), blk, 0, stream>>>(h, ssrc, offs, agg, n, E);
}

extern "C" void kernel_launch(void* const* d_in, const int* in_sizes, int n_in,
                              void* d_out, int out_size, void* d_ws, size_t ws_size,
                              hipStream_t stream)
{
    const float* x    = (const float*)d_in[0];
    const int*   src0 = (const int*)d_in[1];
    const int*   dst0 = (const int*)d_in[2];
    const int*   src1 = (const int*)d_in[3];
    const int*   dst1 = (const int*)d_in[4];
    const int*   src2 = (const int*)d_in[5];
    const int*   dst2 = (const int*)d_in[6];
    const float* Wfc  = (const float*)d_in[10];
    const float* bfc  = (const float*)d_in[11];
    const float* Ws0  = (const float*)d_in[12];
    const float* Wn0  = (const float*)d_in[13];
    const float* b0   = (const float*)d_in[14];
    const float* Ws1  = (const float*)d_in[15];
    const float* Wn1  = (const float*)d_in[16];
    const float* b1   = (const float*)d_in[17];
    const float* Ws2  = (const float*)d_in[18];
    const float* Wn2  = (const float*)d_in[19];
    const float* b2   = (const float*)d_in[20];
    const int E0 = in_sizes[1], E1 = in_sizes[3], E2 = in_sizes[5];

    char* ws = (char*)d_ws;
    unsigned short* h0   = (unsigned short*)ws;                    // 256 MiB
    unsigned short* h1   = (unsigned short*)(ws + (256ULL << 20)); // 128 MiB
    unsigned short* h2   = (unsigned short*)(ws + (384ULL << 20)); //  32 MiB
    unsigned short* agg  = (unsigned short*)(ws + (416ULL << 20)); // 128 MiB
    unsigned short* Wt   = (unsigned short*)(ws + (544ULL << 20)); //   1 MiB
    int*            hist = (int*)(ws + (545ULL << 20));            //   1 MiB
    int*            offs = (int*)(ws + (546ULL << 20));            //   1 MiB
    int*            bsum = (int*)(ws + (547ULL << 20));            //   4 KiB
    int*            ssrc = (int*)(ws + (548ULL << 20));            // <=10.5 MiB

    unsigned short* wfc = Wt;
    unsigned short* ws0 = Wt + 65536;
    unsigned short* wn0 = Wt + 131072;
    unsigned short* ws1 = Wt + 196608;
    unsigned short* wn1 = Wt + 262144;
    unsigned short* ws2 = Wt + 327680;
    unsigned short* wn2 = Wt + 344064;

    const dim3 blk(256);

    // weights -> bf16 transposed [N][K]
    wconv_k<<<dim3(256), blk, 0, stream>>>(Wfc, wfc, 256, 256);
    wconv_k<<<dim3(256), blk, 0, stream>>>(Ws0, ws0, 256, 256);
    wconv_k<<<dim3(256), blk, 0, stream>>>(Wn0, wn0, 256, 256);
    wconv_k<<<dim3(256), blk, 0, stream>>>(Ws1, ws1, 256, 256);
    wconv_k<<<dim3(256), blk, 0, stream>>>(Wn1, wn1, 256, 256);
    wconv_k<<<dim3(64),  blk, 0, stream>>>(Ws2, ws2, 256, 64);
    wconv_k<<<dim3(64),  blk, 0, stream>>>(Wn2, wn2, 256, 64);

    // h0 = relu(x @ Wfc + bfc)   [f32 in, bf16 out]
    gemm_mfma<16, true, false, true, true><<<dim3(N0c / 128), blk, 0, stream>>>(
        x, nullptr, wfc, nullptr, bfc, h0, N0c);

    // ---- layer 0 ----
    build_and_aggregate(h0, src0, dst0, N1c, E0, hist, offs, bsum, ssrc, agg, stream);
    gemm_mfma<16, true, true, false, true><<<dim3(N1c / 128), blk, 0, stream>>>(
        h0, agg, ws0, wn0, b0, h1, N1c);

    // ---- layer 1 ----
    build_and_aggregate(h1, src1, dst1, N2c, E1, hist, offs, bsum, ssrc, agg, stream);
    gemm_mfma<16, true, true, false, true><<<dim3(N2c / 128), blk, 0, stream>>>(
        h1, agg, ws1, wn1, b1, h2, N2c);

    // ---- layer 2: out width 64, f32 out, no relu ----
    build_and_aggregate(h2, src2, dst2, N3c, E2, hist, offs, bsum, ssrc, agg, stream);
    gemm_mfma<4, false, true, false, false><<<dim3(N3c / 128), blk, 0, stream>>>(
        h2, agg, ws2, wn2, b2, (float*)d_out, N3c);
}